// Round 2
// baseline (183.705 us; speedup 1.0000x reference)
//
#include <hip/hip_runtime.h>

// RoIAlign1D: feat [B,T,D] f32, spans [B,K,2] i32, lengths [B] i32 -> out [B,K,P,D] f32
// B=16, T=4096, D=512, K=64, P=16

constexpr int B = 16;
constexpr int T = 4096;
constexpr int D = 512;
constexpr int K = 64;
constexpr int P = 16;

// One block per RoI (b,k): 256 threads = 2 samples (p) per iteration,
// 128 float4 lanes per sample row. Keeps all P samples of a RoI on one CU
// so overlapping source rows (idx1(p) == idx0(p+1)) hit L1/L2.
__global__ __launch_bounds__(256) void roialign1d_kernel(
    const float* __restrict__ feat,
    const int* __restrict__ spans,
    const int* __restrict__ lengths,
    float* __restrict__ out) {

    const int bk = blockIdx.x;        // b*K + k, [0, B*K)
    const int b  = bk >> 6;           // K = 64

    const int Lm1 = lengths[b] - 1;
    int s0 = spans[bk * 2 + 0];
    int s1 = spans[bk * 2 + 1];
    s0 = min(max(s0, 0), Lm1);
    s1 = min(max(s1, 0), Lm1);
    const int s      = min(s0, s1);
    const int e      = max(s0, s1);
    const int seglen = e - s + 1;
    const float segm1f = (float)(seglen - 1);
    const int   segm1i = seglen - 1;

    const int d  = threadIdx.x & 127;   // float4 slot within row
    const int ph = threadIdx.x >> 7;    // which of the 2 samples this iter

    const float4* __restrict__ fb = (const float4*)(feat + (size_t)b * T * D);
    float4* __restrict__ ob = (float4*)(out + (size_t)bk * P * D);

    #pragma unroll
    for (int pp = 0; pp < P; pp += 2) {
        const int p = pp + ph;

        // Exact fp32 replication of the reference linspace math.
        const float t   = (float)p / 15.0f;          // p / (P-1), fp32 divide
        const float idx = t * segm1f;
        const int idx0  = min((int)floorf(idx), segm1i);
        const int idx1  = min(idx0 + 1, segm1i);
        const float w   = idx - (float)idx0;         // after the min, per reference
        const float wm  = 1.0f - w;

        const float4 a = fb[(size_t)(s + idx0) * 128 + d];
        const float4 c = fb[(size_t)(s + idx1) * 128 + d];
        float4 r;
        r.x = wm * a.x + w * c.x;
        r.y = wm * a.y + w * c.y;
        r.z = wm * a.z + w * c.z;
        r.w = wm * a.w + w * c.w;
        ob[p * 128 + d] = r;
    }
}

extern "C" void kernel_launch(void* const* d_in, const int* in_sizes, int n_in,
                              void* d_out, int out_size, void* d_ws, size_t ws_size,
                              hipStream_t stream) {
    const float* feat    = (const float*)d_in[0];
    const int*   spans   = (const int*)d_in[1];
    const int*   lengths = (const int*)d_in[2];
    float*       out     = (float*)d_out;

    roialign1d_kernel<<<B * K, 256, 0, stream>>>(feat, spans, lengths, out);
}